// Round 1
// baseline (81.124 us; speedup 1.0000x reference)
//
#include <hip/hip_runtime.h>
#include <math.h>

#define S 7
#define NB 2
#define NC 20
#define NOBJ 32
#define BATCH 16384
#define CELLS (S * S)                 // 49
#define CH (NB * 5 + NC)              // 30
#define PRED_PER (CELLS * CH)         // 1470
#define LC_W 5.0f
#define LN_W 0.5f

__device__ __forceinline__ float iou_fn(float px, float py, float pw, float ph,
                                        float gx, float gy, float gw, float gh) {
    float px1 = px - pw * 0.5f, py1 = py - ph * 0.5f;
    float px2 = px + pw * 0.5f, py2 = py + ph * 0.5f;
    float gx1 = gx - gw * 0.5f, gy1 = gy - gh * 0.5f;
    float gx2 = gx + gw * 0.5f, gy2 = gy + gh * 0.5f;
    float iw = fmaxf(fminf(px2, gx2) - fmaxf(px1, gx1), 0.0f);
    float ih = fmaxf(fminf(py2, gy2) - fmaxf(py1, gy1), 0.0f);
    float inter = iw * ih;
    float uni = (px2 - px1) * (py2 - py1) + (gx2 - gx1) * (gy2 - gy1) - inter;
    return inter / (uni + 1e-6f);
}

__global__ __launch_bounds__(256) void yolo_loss_main(
    const float* __restrict__ pred, const float* __restrict__ tgt,
    float* __restrict__ partial)
{
    __shared__ float sp[PRED_PER];          // staged predictions for this image
    __shared__ float objBi[NOBJ];           // best IoU per object
    __shared__ float objBox[NOBJ][4];       // cx_rel, cy_rel, w, h
    __shared__ int   objCell[NOBJ];         // -1 if invalid
    __shared__ int   objBj[NOBJ];           // argmax box index
    __shared__ int   objCls[NOBJ];
    __shared__ int   win[CELLS];            // winning object index or -1
    __shared__ unsigned int cmask[CELLS];   // one-hot class bitmask per cell
    __shared__ float wsum[4];

    const int b = blockIdx.x;
    const int tid = threadIdx.x;

    // --- stage predictions (coalesced float2: 5880 B per image, 8B-aligned) ---
    const float2* p2 = (const float2*)(pred + (size_t)b * PRED_PER);
    float2* s2 = (float2*)sp;
    for (int i = tid; i < PRED_PER / 2; i += 256) s2[i] = p2[i];
    __syncthreads();

    // --- phase A: per-object cell assignment + IoU vs both predicted boxes ---
    if (tid < NOBJ) {
        const float* t = tgt + ((size_t)b * NOBJ + tid) * 5;
        float cls = t[0], cx = t[1], cy = t[2], w = t[3], h = t[4];
        int cell = -1, bj = 0, ci = 0;
        float bi = 0.0f, bx0 = 0.f, bx1 = 0.f, bx2 = 0.f, bx3 = 0.f;
        if (cls >= 0.0f) {
            int col = (int)floorf(cx * (float)S);
            col = min(max(col, 0), S - 1);
            int row = (int)floorf(cy * (float)S);
            row = min(max(row, 0), S - 1);
            cell = row * S + col;
            const float* pc = sp + cell * CH;
            float iou0 = iou_fn(pc[0], pc[1], pc[2], pc[3], cx, cy, w, h);
            float iou1 = iou_fn(pc[5], pc[6], pc[7], pc[8], cx, cy, w, h);
            bj = (iou1 > iou0) ? 1 : 0;       // argmax: first index wins ties
            bi = fmaxf(iou0, iou1);
            bx0 = cx * (float)S - (float)col;
            bx1 = cy * (float)S - (float)row;
            bx2 = w; bx3 = h;
            ci = (int)fminf(fmaxf(cls, 0.0f), (float)(NC - 1));
        }
        objCell[tid] = cell;
        objBi[tid] = bi;
        objBj[tid] = bj;
        objCls[tid] = ci;
        objBox[tid][0] = bx0; objBox[tid][1] = bx1;
        objBox[tid][2] = bx2; objBox[tid][3] = bx3;
    }
    __syncthreads();

    // --- phase B: per-cell winner (segment_max + min-index tiebreak) + class mask ---
    if (tid < CELLS) {
        float best = -1.0f;
        int w_ = -1;
        unsigned int m = 0u;
        for (int n = 0; n < NOBJ; ++n) {
            if (objCell[n] == tid) {
                m |= 1u << objCls[n];
                if (objBi[n] > best) { best = objBi[n]; w_ = n; }  // strict > == first-max
            }
        }
        win[tid] = w_;
        cmask[tid] = m;
    }
    __syncthreads();

    // --- phase C: loss accumulation over all 49*30 staged elements ---
    float acc = 0.0f;
    for (int idx = tid; idx < PRED_PER; idx += 256) {
        int c = idx / CH;
        int ch = idx - c * CH;
        float p = sp[idx];
        int w_ = win[c];
        bool obj = (w_ >= 0);
        if (ch < NB * 5) {
            int j = ch / 5;
            int f = ch - j * 5;
            bool isResp = obj && (j == objBj[w_]);
            if (f == 4) {
                if (isResp) {
                    float d = p - objBi[w_];
                    acc += d * d;                         // loss_obj
                } else {
                    acc += LN_W * p * p;                  // loss_noobj
                }
            } else if (isResp) {
                if (f < 2) {
                    float d = p - objBox[w_][f];
                    acc += LC_W * d * d;                  // loss_xy
                } else {
                    float d = sqrtf(fmaxf(p, 0.0f)) - sqrtf(objBox[w_][f]);
                    acc += LC_W * d * d;                  // loss_wh
                }
            }
        } else if (obj) {
            int k = ch - NB * 5;
            float g = (float)((cmask[c] >> k) & 1u);
            acc += p * p + g * (1.0f - 2.0f * p);         // (p-g)^2, g in {0,1}
        }
    }

    // --- block reduce (4 waves of 64) ---
    for (int off = 32; off > 0; off >>= 1) acc += __shfl_down(acc, off, 64);
    int wave = tid >> 6;
    if ((tid & 63) == 0) wsum[wave] = acc;
    __syncthreads();
    if (tid == 0) partial[b] = wsum[0] + wsum[1] + wsum[2] + wsum[3];
}

__global__ __launch_bounds__(256) void yolo_loss_reduce(
    const float* __restrict__ partial, float* __restrict__ out)
{
    __shared__ float wsum[4];
    float acc = 0.0f;
    for (int i = threadIdx.x; i < BATCH; i += 256) acc += partial[i];
    for (int off = 32; off > 0; off >>= 1) acc += __shfl_down(acc, off, 64);
    int wave = threadIdx.x >> 6;
    if ((threadIdx.x & 63) == 0) wsum[wave] = acc;
    __syncthreads();
    if (threadIdx.x == 0) out[0] = (wsum[0] + wsum[1] + wsum[2] + wsum[3]) / (float)BATCH;
}

extern "C" void kernel_launch(void* const* d_in, const int* in_sizes, int n_in,
                              void* d_out, int out_size, void* d_ws, size_t ws_size,
                              hipStream_t stream) {
    const float* pred = (const float*)d_in[0];   // (BATCH, S, S, 30) fp32
    const float* tgt  = (const float*)d_in[1];   // (BATCH, NOBJ, 5) fp32
    float* out = (float*)d_out;
    float* partial = (float*)d_ws;               // BATCH floats = 64 KB

    yolo_loss_main<<<BATCH, 256, 0, stream>>>(pred, tgt, partial);
    yolo_loss_reduce<<<1, 256, 0, stream>>>(partial, out);
}

// Round 2
// 24.711 us; speedup vs baseline: 3.2829x; 3.2829x over previous
//
#include <hip/hip_runtime.h>
#include <math.h>

#define S 7
#define NB 2
#define NC 20
#define NOBJ 32
#define BATCH 16384
#define CELLS 49            // S*S
#define CH 30               // NB*5+NC
#define PRED_PER 1470       // CELLS*CH
#define LC_W 5.0f
#define LN_W 0.5f
#define IPB 4               // images per block (one per wave)

__device__ __forceinline__ float iou_fn(float px, float py, float pw, float ph,
                                        float gx, float gy, float gw, float gh) {
    float px1 = px - pw * 0.5f, py1 = py - ph * 0.5f;
    float px2 = px + pw * 0.5f, py2 = py + ph * 0.5f;
    float gx1 = gx - gw * 0.5f, gy1 = gy - gh * 0.5f;
    float gx2 = gx + gw * 0.5f, gy2 = gy + gh * 0.5f;
    float iw = fmaxf(fminf(px2, gx2) - fmaxf(px1, gx1), 0.0f);
    float ih = fmaxf(fminf(py2, gy2) - fmaxf(py1, gy1), 0.0f);
    float inter = iw * ih;
    float uni = (px2 - px1) * (py2 - py1) + (gx2 - gx1) * (gy2 - gy1) - inter;
    return inter / (uni + 1e-6f);
}

__global__ __launch_bounds__(256) void yolo_main(
    const float* __restrict__ pred, const float* __restrict__ tgt,
    float* __restrict__ partial)
{
    // per-wave (per-image) winner tables
    __shared__ unsigned long long cellkey[IPB][CELLS]; // (iou_bits<<32)|(~obj_idx), 0 = no object
    __shared__ unsigned int      cmaskS[IPB][CELLS];   // one-hot class bitmask

    const int lane = threadIdx.x & 63;
    const int wv   = threadIdx.x >> 6;
    const int b    = blockIdx.x * IPB + wv;

    if (lane < CELLS) { cellkey[wv][lane] = 0ull; cmaskS[wv][lane] = 0u; }

    // ---- prefetch own cell's 30 channels (lane = cell), issued first ----
    const int cell = (lane < CELLS) ? lane : CELLS - 1;
    const float2* cbase = (const float2*)(pred + (size_t)b * PRED_PER + cell * CH);
    float2 pv[15];
    #pragma unroll
    for (int k = 0; k < 15; ++k) pv[k] = cbase[k];

    // ---- phase A: lane = object (0..31); all lanes execute, masked ----
    const int ol = (lane < NOBJ) ? lane : NOBJ - 1;
    const float* t = tgt + ((size_t)b * NOBJ + ol) * 5;
    float cls = t[0], cx = t[1], cy = t[2], tw = t[3], th = t[4];
    bool valid = (lane < NOBJ) && (cls >= 0.0f);
    int col = (int)floorf(cx * 7.0f); col = min(max(col, 0), 6);
    int row = (int)floorf(cy * 7.0f); row = min(max(row, 0), 6);
    int ocell = row * 7 + col;
    const float* pc = pred + (size_t)b * PRED_PER + ocell * CH;
    float iou0 = iou_fn(pc[0], pc[1], pc[2], pc[3], cx, cy, tw, th);
    float iou1 = iou_fn(pc[5], pc[6], pc[7], pc[8], cx, cy, tw, th);
    float bi = fmaxf(iou0, iou1);
    int   bj = (iou1 > iou0) ? 1 : 0;            // argmax, first index wins ties
    float bx = cx * 7.0f - (float)col;
    float by = cy * 7.0f - (float)row;
    if (valid) {
        // max iou; equal iou -> smaller object index (matches segment_max + min-index)
        unsigned long long key =
            ((unsigned long long)__float_as_uint(bi) << 32)
          | (unsigned long long)(0xffffffffu - (unsigned)lane);
        atomicMax(&cellkey[wv][ocell], key);
        atomicOr(&cmaskS[wv][ocell], 1u << (int)cls);
    }
    __syncthreads();

    // ---- phase C: lane = cell; winner data via shfl from winning object's lane ----
    unsigned long long key = cellkey[wv][cell];
    unsigned int m = cmaskS[wv][cell];
    bool obj = (lane < CELLS) && (key != 0ull);
    int  w_  = (int)(0xffffffffu - (unsigned)(key & 0xffffffffull));
    int  wsafe = obj ? w_ : 0;
    float biou = __uint_as_float((unsigned)(key >> 32));
    float gx  = __shfl(bx, wsafe);
    float gy  = __shfl(by, wsafe);
    float gw  = __shfl(tw, wsafe);
    float gh  = __shfl(th, wsafe);
    int   gbj = __shfl(bj, wsafe);

    float p[30];
    #pragma unroll
    for (int k = 0; k < 15; ++k) { p[2*k] = pv[k].x; p[2*k+1] = pv[k].y; }

    float acc = 0.0f;
    float fobj = obj ? 1.0f : 0.0f;
    float sgw = sqrtf(gw), sgh = sqrtf(gh);
    #pragma unroll
    for (int j = 0; j < 2; ++j) {
        float r = (obj && gbj == j) ? 1.0f : 0.0f;
        float bx_ = p[j*5+0], by_ = p[j*5+1], bw_ = p[j*5+2], bh_ = p[j*5+3], bc_ = p[j*5+4];
        float dx = bx_ - gx, dy = by_ - gy;
        float dw = sqrtf(fmaxf(bw_, 0.0f)) - sgw;
        float dh = sqrtf(fmaxf(bh_, 0.0f)) - sgh;
        float dcf = bc_ - biou;
        acc += r * (LC_W * (dx*dx + dy*dy + dw*dw + dh*dh) + dcf*dcf);
        acc += (1.0f - r) * (LN_W * bc_ * bc_);   // noobj: every non-responsible box
    }
    #pragma unroll
    for (int k = 0; k < NC; ++k) {
        float pcv = p[10 + k];
        float g = (float)((m >> k) & 1u);
        acc += fobj * (pcv * pcv + g * (1.0f - 2.0f * pcv));   // (p-g)^2, g in {0,1}
    }
    if (lane >= CELLS) acc = 0.0f;

    // wave reduce, lane 0 writes per-image partial
    #pragma unroll
    for (int off = 32; off; off >>= 1) acc += __shfl_down(acc, off);
    if (lane == 0) partial[b] = acc;
}

__global__ __launch_bounds__(1024) void yolo_reduce(
    const float* __restrict__ partial, float* __restrict__ out)
{
    __shared__ float ws[16];
    float acc = 0.0f;
    #pragma unroll
    for (int k = 0; k < 4; ++k) {
        float4 v = ((const float4*)partial)[threadIdx.x * 4 + k];
        acc += v.x + v.y + v.z + v.w;
    }
    #pragma unroll
    for (int off = 32; off; off >>= 1) acc += __shfl_down(acc, off);
    if ((threadIdx.x & 63) == 0) ws[threadIdx.x >> 6] = acc;
    __syncthreads();
    if (threadIdx.x == 0) {
        float s = 0.0f;
        #pragma unroll
        for (int i = 0; i < 16; ++i) s += ws[i];
        out[0] = s / (float)BATCH;
    }
}

extern "C" void kernel_launch(void* const* d_in, const int* in_sizes, int n_in,
                              void* d_out, int out_size, void* d_ws, size_t ws_size,
                              hipStream_t stream) {
    const float* pred = (const float*)d_in[0];   // (BATCH, S, S, 30) fp32
    const float* tgt  = (const float*)d_in[1];   // (BATCH, NOBJ, 5) fp32
    float* out = (float*)d_out;
    float* partial = (float*)d_ws;               // BATCH floats = 64 KB

    yolo_main<<<BATCH / IPB, 256, 0, stream>>>(pred, tgt, partial);
    yolo_reduce<<<1, 1024, 0, stream>>>(partial, out);
}